// Round 5
// baseline (194.186 us; speedup 1.0000x reference)
//
#include <hip/hip_runtime.h>

#define B_SZ 2
#define LSEQ 2048
#define NHh 24
#define DHh 64
#define DSs 128
#define TCH 64                  // chunk length
#define NC  (LSEQ / TCH)        // 32 chunks
#define BH  (B_SZ * NHh)        // 48

// ws layout: S (fp32) | G (bf16, [bh][c][d][s]) | H (bf16, same layout)
#define S_ELEMS   (BH * LSEQ)
#define G_ELEMS   ((size_t)BH * NC * DSs * DHh)
#define WS_S_BYTES ((size_t)S_ELEMS * 4)
#define WS_G_BYTES (G_ELEMS * 2)
#define WS_REQ     (WS_S_BYTES + 2 * WS_G_BYTES)

#define SP  136   // padded row length for k=128 (s) tiles: 272 B stride, 16B-aligned
#define UP  72    // padded row length for k=64  (u) tiles: 144 B stride, 16B-aligned

typedef __attribute__((ext_vector_type(8))) short bf16x8;
typedef __attribute__((ext_vector_type(4))) float f32x4;

__device__ __forceinline__ unsigned short f2bf(float f) {
    union { float f; unsigned u; } v; v.f = f;
    unsigned r = ((v.u >> 16) & 1u) + 0x7FFFu;
    return (unsigned short)((v.u + r) >> 16);
}
__device__ __forceinline__ float bf2f(unsigned short h) {
    union { unsigned u; float f; } v; v.u = ((unsigned)h) << 16; return v.f;
}
__device__ __forceinline__ unsigned pk2(float a, float b) {
    return (unsigned)f2bf(a) | ((unsigned)f2bf(b) << 16);
}

// ============ K1: cumsum S + G = (f*X)^T-major MFMA, G_ws in [d][s] ============
// (256,4): LDS 27.9KB allows 5/CU, VGPR ~80 fits the 128 cap -> 4 blocks/CU.
__global__ __launch_bounds__(256, 4)
void k1_chunk(const float* __restrict__ x, const float* __restrict__ A,
              const float* __restrict__ Bm, const float* __restrict__ dp,
              float* __restrict__ S_ws, unsigned short* __restrict__ G_ws) {
    __shared__ __align__(16) union K1SM {
        struct {
            unsigned short bt[DSs][UP];
            unsigned short xt[DHh][UP];
            float          f[TCH];
        } a;
        unsigned short g[TCH][SP];
    } sm;

    const int c  = blockIdx.x & (NC - 1);
    const int bh = blockIdx.x >> 5;
    const int nh = bh % NHh; const int b = bh / NHh;
    const int tid = threadIdx.x;
    const int lane = tid & 63;
    const int w = tid >> 6;

    const size_t row0 = (size_t)(b * LSEQ + c * TCH) * NHh + nh;
    const int u = tid >> 2;
    const int q = tid & 3;
    const float* Brow = Bm + (row0 + (size_t)u * NHh) * DSs;
    const float* xrow = x  + (row0 + (size_t)u * NHh) * DHh;
    float4 bv[8], xv[4];
    #pragma unroll
    for (int j = 0; j < 8; ++j) bv[j] = *(const float4*)(Brow + (j * 4 + q) * 4);
    #pragma unroll
    for (int j = 0; j < 4; ++j) xv[j] = *(const float4*)(xrow + (j * 4 + q) * 4);

    #pragma unroll
    for (int j = 0; j < 8; ++j) {
        const int s = (j * 4 + q) * 4;
        sm.a.bt[s + 0][u] = f2bf(bv[j].x);
        sm.a.bt[s + 1][u] = f2bf(bv[j].y);
        sm.a.bt[s + 2][u] = f2bf(bv[j].z);
        sm.a.bt[s + 3][u] = f2bf(bv[j].w);
    }

    if (tid < 64) {   // wave0: log-decay cumsum
        float a  = A[row0 + (size_t)tid * NHh];
        float z  = a + dp[nh];
        float sp = (z > 20.0f) ? z : log1pf(expf(z));
        float la = -sp * fabsf(a);
        #pragma unroll
        for (int off = 1; off < 64; off <<= 1) {
            float v = __shfl_up(la, off, 64);
            if (lane >= off) la += v;
        }
        S_ws[(size_t)bh * LSEQ + c * TCH + tid] = la;
        float s63 = __shfl(la, 63, 64);
        sm.a.f[tid] = expf(s63 - la);
    }
    __syncthreads();

    const float f = sm.a.f[u];
    #pragma unroll
    for (int j = 0; j < 4; ++j) {
        const int d = (j * 4 + q) * 4;
        sm.a.xt[d + 0][u] = f2bf(xv[j].x * f);
        sm.a.xt[d + 1][u] = f2bf(xv[j].y * f);
        sm.a.xt[d + 2][u] = f2bf(xv[j].z * f);
        sm.a.xt[d + 3][u] = f2bf(xv[j].w * f);
    }
    __syncthreads();

    const int fr = lane >> 4, fc = lane & 15;
    bf16x8 afr0 = *(const bf16x8*)&sm.a.xt[16 * w + fc][fr * 8];
    bf16x8 afr1 = *(const bf16x8*)&sm.a.xt[16 * w + fc][32 + fr * 8];
    f32x4 accs[8];
    #pragma unroll
    for (int st = 0; st < 8; ++st) {
        f32x4 acc = {0.f, 0.f, 0.f, 0.f};
        bf16x8 b0 = *(const bf16x8*)&sm.a.bt[st * 16 + fc][fr * 8];
        bf16x8 b1 = *(const bf16x8*)&sm.a.bt[st * 16 + fc][32 + fr * 8];
        acc = __builtin_amdgcn_mfma_f32_16x16x32_bf16(afr0, b0, acc, 0, 0, 0);
        acc = __builtin_amdgcn_mfma_f32_16x16x32_bf16(afr1, b1, acc, 0, 0, 0);
        accs[st] = acc;
    }
    __syncthreads();

    #pragma unroll
    for (int st = 0; st < 8; ++st) {
        #pragma unroll
        for (int r = 0; r < 4; ++r)
            sm.g[16 * w + fr * 4 + r][st * 16 + fc] = f2bf(accs[st][r]);
    }
    __syncthreads();

    const int gr = tid >> 2;
    unsigned short* gbase = G_ws + (((size_t)bh * NC + c) * DHh + gr) * DSs;
    #pragma unroll
    for (int j = 0; j < 4; ++j) {
        const int s = (j * 4 + q) * 8;
        *(uint4*)(gbase + s) = *(const uint4*)&sm.g[gr][s];
    }
}

// ============ K2: chunk-level scan over [d][s] planes ============
// 768 blocks x 256 thr, ONE d-row per wave (3072 wave-units = 48bh x 64d).
// 12 scan waves/CU (vs 3 before); depth-16 rolling prefetch, 4B/lane coalesced.
__global__ __launch_bounds__(256)
void k2_scan(const float* __restrict__ S_ws, const unsigned short* __restrict__ G_ws,
             unsigned short* __restrict__ H_ws) {
    const int w    = threadIdx.x >> 6;
    const int lane = threadIdx.x & 63;
    const int unit = (blockIdx.x << 2) | w;    // 0..3071
    const int bh   = unit >> 6;
    const int d    = unit & 63;
    const int s0   = lane * 2;

    float h0 = 0.f, h1 = 0.f;
    size_t base = (((size_t)bh * NC) * DHh + d) * DSs + s0;
    const size_t cstride = (size_t)DHh * DSs;
    const float* Se = S_ws + (size_t)bh * LSEQ + (TCH - 1);

    unsigned g[16]; float sv[16];
    #pragma unroll
    for (int j = 0; j < 16; ++j) {
        g[j]  = *(const unsigned*)(G_ws + base + (size_t)j * cstride);
        sv[j] = Se[(size_t)j * TCH];
    }
    #pragma unroll
    for (int c = 0; c < NC; c += 16) {
        #pragma unroll
        for (int j = 0; j < 16; ++j) {
            const int cc = c + j;
            *(unsigned*)(H_ws + base + (size_t)cc * cstride) = pk2(h0, h1);
            const float e = expf(sv[j]);
            h0 = fmaf(e, h0, bf2f((unsigned short)(g[j] & 0xffff)));
            h1 = fmaf(e, h1, bf2f((unsigned short)(g[j] >> 16)));
            if (cc + 16 < NC) {
                g[j]  = *(const unsigned*)(G_ws + base + (size_t)(cc + 16) * cstride);
                sv[j] = Se[(size_t)(cc + 16) * TCH];
            }
        }
    }
}

// ============ K3: W = mask*exp o (C.B^T); y = W.X + E o (C.H^T), all MFMA ============
// sB and sH SHARE one swizzled 16KB tile: B is read only in the W phase; H is
// written into the same space after a barrier and read in the Y phase.
// LDS 34.9KB + (256,4) -> 4 blocks/CU (16 waves, was 12).
__global__ __launch_bounds__(256, 4)
void k3_y(const float* __restrict__ x, const float* __restrict__ Bm,
          const float* __restrict__ Cm, const float* __restrict__ S_ws,
          const unsigned short* __restrict__ H_ws, float* __restrict__ y) {
    __shared__ __align__(16) unsigned short sBH[TCH * DSs]; // B (W phase) / H (Y phase)
    __shared__ __align__(16) unsigned short sW[TCH][UP];    // W [t][u]
    __shared__ __align__(16) unsigned short sXT[DHh][UP];   // X^T [d][u]
    __shared__ float sS[TCH];
    __shared__ float sEt[TCH];

    const int c  = blockIdx.x & (NC - 1);
    const int bh = blockIdx.x >> 5;
    const int nh = bh % NHh; const int b = bh / NHh;
    const int tid = threadIdx.x;
    const int lane = tid & 63;
    const int w = tid >> 6;
    const int fr = lane >> 4, fc = lane & 15;
    const int t0w = 16 * w;

    const size_t row0 = (size_t)(b * LSEQ + c * TCH) * NHh + nh;
    const int rr = tid >> 2;
    const int q  = tid & 3;
    const float* Brow = Bm + (row0 + (size_t)rr * NHh) * DSs;
    const float* xrow = x  + (row0 + (size_t)rr * NHh) * DHh;
    const unsigned short* Hrow = H_ws + (((size_t)bh * NC + c) * DHh + rr) * DSs;
    float4 bv[8], xv[4];
    uint4  hv[4];
    #pragma unroll
    for (int j = 0; j < 8; ++j) bv[j] = *(const float4*)(Brow + (j * 4 + q) * 4);
    #pragma unroll
    for (int j = 0; j < 4; ++j) xv[j] = *(const float4*)(xrow + (j * 4 + q) * 4);
    #pragma unroll
    for (int j = 0; j < 4; ++j) hv[j] = *(const uint4*)(Hrow + (j * 4 + q) * 8);

    const float* Cfr = Cm + (row0 + (size_t)(t0w + fc) * NHh) * DSs + fr * 8;
    float4 cf[8];
    #pragma unroll
    for (int kb = 0; kb < 4; ++kb) {
        cf[2 * kb]     = *(const float4*)(Cfr + kb * 32);
        cf[2 * kb + 1] = *(const float4*)(Cfr + kb * 32 + 4);
    }

    if (tid < 64) {
        float svv = S_ws[(size_t)bh * LSEQ + c * TCH + tid];
        sS[tid]  = svv;
        sEt[tid] = expf(svv);
    }

    // build C A-fragments in registers (frees cf)
    bf16x8 ca[4];
    #pragma unroll
    for (int kb = 0; kb < 4; ++kb) {
        bf16x8 t;
        t[0] = (short)f2bf(cf[2 * kb].x);     t[1] = (short)f2bf(cf[2 * kb].y);
        t[2] = (short)f2bf(cf[2 * kb].z);     t[3] = (short)f2bf(cf[2 * kb].w);
        t[4] = (short)f2bf(cf[2 * kb + 1].x); t[5] = (short)f2bf(cf[2 * kb + 1].y);
        t[6] = (short)f2bf(cf[2 * kb + 1].z); t[7] = (short)f2bf(cf[2 * kb + 1].w);
        ca[kb] = t;
    }

    // stage B (swizzled) and X^T; H stays in registers until after the W phase
    const int rsw = (rr & 15) << 3;   // swizzle: elem bits[6:3] ^= row&15
    #pragma unroll
    for (int j = 0; j < 8; ++j) {
        const int s = (j * 4 + q) * 4;
        *(uint2*)&sBH[rr * DSs + (s ^ rsw)] =
            make_uint2(pk2(bv[j].x, bv[j].y), pk2(bv[j].z, bv[j].w));
    }
    #pragma unroll
    for (int j = 0; j < 4; ++j) {
        const int d = (j * 4 + q) * 4;
        sXT[d + 0][rr] = f2bf(xv[j].x);
        sXT[d + 1][rr] = f2bf(xv[j].y);
        sXT[d + 2][rr] = f2bf(xv[j].z);
        sXT[d + 3][rr] = f2bf(xv[j].w);
    }
    __syncthreads();

    // ---- W phase: wave w owns t-rows [t0w, t0w+16) ----
    float st4[4];
    #pragma unroll
    for (int r = 0; r < 4; ++r) st4[r] = sS[t0w + fr * 4 + r];

    const int csw = fc << 3;          // read-side swizzle
    #pragma unroll
    for (int ut = 0; ut < 4; ++ut) {
        const int u0 = ut * 16;
        unsigned short wv[4] = {0, 0, 0, 0};
        if (ut <= w) {   // tiles fully in the future are all-zero
            f32x4 acc = {0.f, 0.f, 0.f, 0.f};
            #pragma unroll
            for (int kb = 0; kb < 4; ++kb) {
                bf16x8 bb = *(const bf16x8*)
                    &sBH[(u0 + fc) * DSs + ((kb * 32 + fr * 8) ^ csw)];
                acc = __builtin_amdgcn_mfma_f32_16x16x32_bf16(ca[kb], bb, acc, 0, 0, 0);
            }
            const float su = sS[u0 + fc];
            const int   uu = u0 + fc;
            #pragma unroll
            for (int r = 0; r < 4; ++r) {
                const int t = t0w + fr * 4 + r;
                const float dd = fminf(st4[r] - su, 0.f);
                const float val = (uu <= t) ? acc[r] * expf(dd) : 0.f;
                wv[r] = f2bf(val);
            }
        }
        #pragma unroll
        for (int r = 0; r < 4; ++r) sW[t0w + fr * 4 + r][u0 + fc] = wv[r];
    }

    __syncthreads();   // all sB reads done -> safe to overwrite with H
    #pragma unroll
    for (int j = 0; j < 4; ++j) {
        const int s = (j * 4 + q) * 8;
        *(uint4*)&sBH[rr * DSs + (s ^ rsw)] = hv[j];
    }
    __syncthreads();

    // ---- Y phase: acc = C.H^T (K=128), scale by E_t, then += W.X (K=64) ----
    bf16x8 wa0 = *(const bf16x8*)&sW[t0w + fc][fr * 8];
    bf16x8 wa1;
    if (w >= 2) wa1 = *(const bf16x8*)&sW[t0w + fc][32 + fr * 8];
    float et4[4];
    #pragma unroll
    for (int r = 0; r < 4; ++r) et4[r] = sEt[t0w + fr * 4 + r];

    #pragma unroll
    for (int dt = 0; dt < 4; ++dt) {
        const int d0 = dt * 16;
        f32x4 acc = {0.f, 0.f, 0.f, 0.f};
        #pragma unroll
        for (int kb = 0; kb < 4; ++kb) {
            bf16x8 hb = *(const bf16x8*)
                &sBH[(d0 + fc) * DSs + ((kb * 32 + fr * 8) ^ csw)];
            acc = __builtin_amdgcn_mfma_f32_16x16x32_bf16(ca[kb], hb, acc, 0, 0, 0);
        }
        #pragma unroll
        for (int r = 0; r < 4; ++r) acc[r] *= et4[r];
        bf16x8 xb0 = *(const bf16x8*)&sXT[d0 + fc][fr * 8];
        acc = __builtin_amdgcn_mfma_f32_16x16x32_bf16(wa0, xb0, acc, 0, 0, 0);
        if (w >= 2) {
            bf16x8 xb1 = *(const bf16x8*)&sXT[d0 + fc][32 + fr * 8];
            acc = __builtin_amdgcn_mfma_f32_16x16x32_bf16(wa1, xb1, acc, 0, 0, 0);
        }
        float* yout = y + (row0 + (size_t)(t0w + fr * 4) * NHh) * DHh + d0 + fc;
        #pragma unroll
        for (int r = 0; r < 4; ++r) yout[(size_t)r * NHh * DHh] = acc[r];
    }
}

// ============ fallback (R2 kernel) ============
__device__ __forceinline__ void gload_lds16(const float* g, void* l) {
    __builtin_amdgcn_global_load_lds(
        (const __attribute__((address_space(1))) void*)g,
        (__attribute__((address_space(3))) void*)l, 16, 0, 0);
}
__device__ __forceinline__ void gload_lds4(const float* g, float* l) {
    __builtin_amdgcn_global_load_lds(
        (const __attribute__((address_space(1))) void*)g,
        (__attribute__((address_space(3))) void*)l, 4, 0, 0);
}
#define F_DBLK 4
#define F_DPW 16
#define F_TCH 32
#define F_NCH (LSEQ / F_TCH)
__global__ __launch_bounds__(256, 1)
void ssm_scan_fb(const float* __restrict__ x, const float* __restrict__ A,
                 const float* __restrict__ Bm, const float* __restrict__ Cm,
                 const float* __restrict__ dp, float* __restrict__ y) {
    __shared__ float s_abar[LSEQ];
    __shared__ float s_B[2][F_TCH][DSs];
    __shared__ float s_C[2][F_TCH][DSs];
    __shared__ float s_x[2][F_TCH][F_DPW];
    const int blk = blockIdx.x;
    const int dblk = blk % F_DBLK, bh = blk / F_DBLK;
    const int nh = bh % NHh, b = bh / NHh;
    const float dpv = dp[nh];
    for (int i = threadIdx.x; i < LSEQ; i += 256) {
        float a = A[(b * LSEQ + i) * NHh + nh];
        float z = a + dpv;
        float sp = (z > 20.0f) ? z : log1pf(expf(z));
        s_abar[i] = expf(-sp * fabsf(a));
    }
    const int tid = threadIdx.x, wid = tid >> 6, lane = tid & 63;
    const int dloc = tid >> 4, sg = tid & 15, sb = sg * 8;
    const size_t bh_off = (size_t)(b * LSEQ) * NHh + nh;
    const float* Bbase = Bm + bh_off * DSs;
    const float* Cbase = Cm + bh_off * DSs;
    const float* xbase = x + bh_off * DHh + dblk * F_DPW;
    float* yp = y + bh_off * DHh + dblk * F_DPW + dloc;
    const int RSTRIDE = NHh * DSs, XSTRIDE = NHh * DHh;
    auto stage = [&](int buf, int t0) {
        #pragma unroll
        for (int j = 0; j < 4; ++j) {
            const int r0 = (wid * 4 + j) * 2, r = r0 + (lane >> 5), col = (lane & 31) * 4;
            gload_lds16(Bbase + (size_t)(t0 + r) * RSTRIDE + col, &s_B[buf][r0][0]);
            gload_lds16(Cbase + (size_t)(t0 + r) * RSTRIDE + col, &s_C[buf][r0][0]);
        }
        #pragma unroll
        for (int j = 0; j < 2; ++j) {
            const int idx = (wid * 2 + j) * 64 + lane, t = idx >> 4, dc = idx & 15;
            gload_lds4(xbase + (size_t)(t0 + t) * XSTRIDE + dc, &s_x[buf][(wid * 2 + j) * 4][0]);
        }
    };
    stage(0, 0);
    __syncthreads();
    float h0=0,h1=0,h2=0,h3=0,h4=0,h5=0,h6=0,h7=0;
    for (int c = 0; c < F_NCH; ++c) {
        const int buf = c & 1;
        if (c + 1 < F_NCH) stage(buf ^ 1, (c + 1) * F_TCH);
        const int t0 = c * F_TCH;
        #pragma unroll 4
        for (int tt = 0; tt < F_TCH; ++tt) {
            const int t = t0 + tt;
            const float a = s_abar[t], xd = s_x[buf][tt][dloc];
            const float4* Br = (const float4*)&s_B[buf][tt][sb];
            const float4* Cr = (const float4*)&s_C[buf][tt][sb];
            const float4 B0 = Br[0], B1 = Br[1], C0 = Cr[0], C1 = Cr[1];
            h0 = fmaf(a, h0, xd * B0.x); h1 = fmaf(a, h1, xd * B0.y);
            h2 = fmaf(a, h2, xd * B0.z); h3 = fmaf(a, h3, xd * B0.w);
            h4 = fmaf(a, h4, xd * B1.x); h5 = fmaf(a, h5, xd * B1.y);
            h6 = fmaf(a, h6, xd * B1.z); h7 = fmaf(a, h7, xd * B1.w);
            float p0 = h0 * C0.x; p0 = fmaf(h1, C0.y, p0); p0 = fmaf(h2, C0.z, p0); p0 = fmaf(h3, C0.w, p0);
            float p1 = h4 * C1.x; p1 = fmaf(h5, C1.y, p1); p1 = fmaf(h6, C1.z, p1); p1 = fmaf(h7, C1.w, p1);
            float p = p0 + p1;
            p += __shfl_xor(p, 1, 64); p += __shfl_xor(p, 2, 64);
            p += __shfl_xor(p, 4, 64); p += __shfl_xor(p, 8, 64);
            if (sg == 0) yp[(size_t)t * XSTRIDE] = p;
        }
        __syncthreads();
    }
}

extern "C" void kernel_launch(void* const* d_in, const int* in_sizes, int n_in,
                              void* d_out, int out_size, void* d_ws, size_t ws_size,
                              hipStream_t stream) {
    const float* x  = (const float*)d_in[0];
    const float* A  = (const float*)d_in[1];
    const float* Bm = (const float*)d_in[2];
    const float* Cm = (const float*)d_in[3];
    const float* dp = (const float*)d_in[4];
    float* y = (float*)d_out;

    if (ws_size >= WS_REQ) {
        float* S_ws = (float*)d_ws;
        unsigned short* G_ws = (unsigned short*)((char*)d_ws + WS_S_BYTES);
        unsigned short* H_ws = G_ws + G_ELEMS;
        hipLaunchKernelGGL(k1_chunk, dim3(BH * NC), dim3(256), 0, stream,
                           x, A, Bm, dp, S_ws, G_ws);
        hipLaunchKernelGGL(k2_scan, dim3(BH * 16), dim3(256), 0, stream,
                           S_ws, G_ws, H_ws);
        hipLaunchKernelGGL(k3_y, dim3(BH * NC), dim3(256), 0, stream,
                           x, Bm, Cm, S_ws, H_ws, y);
    } else {
        hipLaunchKernelGGL(ssm_scan_fb, dim3(BH * F_DBLK), dim3(256), 0, stream,
                           x, A, Bm, Cm, dp, y);
    }
}

// Round 6
// 184.334 us; speedup vs baseline: 1.0534x; 1.0534x over previous
//
#include <hip/hip_runtime.h>

#define B_SZ 2
#define LSEQ 2048
#define NHh 24
#define DHh 64
#define DSs 128
#define TCH 64                  // chunk length
#define NC  (LSEQ / TCH)        // 32 chunks
#define BH  (B_SZ * NHh)        // 48

// ws layout: S (fp32) | G (bf16, [bh][c][d][s]) | H (bf16, same layout)
#define S_ELEMS   (BH * LSEQ)
#define G_ELEMS   ((size_t)BH * NC * DSs * DHh)
#define WS_S_BYTES ((size_t)S_ELEMS * 4)
#define WS_G_BYTES (G_ELEMS * 2)
#define WS_REQ     (WS_S_BYTES + 2 * WS_G_BYTES)

#define SP  136   // padded row length for k=128 (s) tiles: 272 B stride, 16B-aligned
#define UP  72    // padded row length for k=64  (u) tiles: 144 B stride, 16B-aligned

typedef __attribute__((ext_vector_type(8))) short bf16x8;
typedef __attribute__((ext_vector_type(4))) float f32x4;

__device__ __forceinline__ unsigned short f2bf(float f) {
    union { float f; unsigned u; } v; v.f = f;
    unsigned r = ((v.u >> 16) & 1u) + 0x7FFFu;
    return (unsigned short)((v.u + r) >> 16);
}
__device__ __forceinline__ float bf2f(unsigned short h) {
    union { unsigned u; float f; } v; v.u = ((unsigned)h) << 16; return v.f;
}
__device__ __forceinline__ unsigned pk2(float a, float b) {
    return (unsigned)f2bf(a) | ((unsigned)f2bf(b) << 16);
}

// ============ K1: cumsum S + G = (f*X)^T-major MFMA, G_ws in [d][s] ============
// (twice-verified R3 version: union G staging, coalesced uint4 copy-out)
__global__ __launch_bounds__(256, 3)
void k1_chunk(const float* __restrict__ x, const float* __restrict__ A,
              const float* __restrict__ Bm, const float* __restrict__ dp,
              float* __restrict__ S_ws, unsigned short* __restrict__ G_ws) {
    __shared__ __align__(16) union K1SM {
        struct {
            unsigned short bt[DSs][UP];
            unsigned short xt[DHh][UP];
            float          f[TCH];
        } a;
        unsigned short g[TCH][SP];
    } sm;

    const int c  = blockIdx.x & (NC - 1);
    const int bh = blockIdx.x >> 5;
    const int nh = bh % NHh; const int b = bh / NHh;
    const int tid = threadIdx.x;
    const int lane = tid & 63;
    const int w = tid >> 6;

    const size_t row0 = (size_t)(b * LSEQ + c * TCH) * NHh + nh;
    const int u = tid >> 2;
    const int q = tid & 3;
    const float* Brow = Bm + (row0 + (size_t)u * NHh) * DSs;
    const float* xrow = x  + (row0 + (size_t)u * NHh) * DHh;
    float4 bv[8], xv[4];
    #pragma unroll
    for (int j = 0; j < 8; ++j) bv[j] = *(const float4*)(Brow + (j * 4 + q) * 4);
    #pragma unroll
    for (int j = 0; j < 4; ++j) xv[j] = *(const float4*)(xrow + (j * 4 + q) * 4);

    #pragma unroll
    for (int j = 0; j < 8; ++j) {
        const int s = (j * 4 + q) * 4;
        sm.a.bt[s + 0][u] = f2bf(bv[j].x);
        sm.a.bt[s + 1][u] = f2bf(bv[j].y);
        sm.a.bt[s + 2][u] = f2bf(bv[j].z);
        sm.a.bt[s + 3][u] = f2bf(bv[j].w);
    }

    if (tid < 64) {   // wave0: log-decay cumsum
        float a  = A[row0 + (size_t)tid * NHh];
        float z  = a + dp[nh];
        float sp = (z > 20.0f) ? z : log1pf(expf(z));
        float la = -sp * fabsf(a);
        #pragma unroll
        for (int off = 1; off < 64; off <<= 1) {
            float v = __shfl_up(la, off, 64);
            if (lane >= off) la += v;
        }
        S_ws[(size_t)bh * LSEQ + c * TCH + tid] = la;
        float s63 = __shfl(la, 63, 64);
        sm.a.f[tid] = expf(s63 - la);
    }
    __syncthreads();

    const float f = sm.a.f[u];
    #pragma unroll
    for (int j = 0; j < 4; ++j) {
        const int d = (j * 4 + q) * 4;
        sm.a.xt[d + 0][u] = f2bf(xv[j].x * f);
        sm.a.xt[d + 1][u] = f2bf(xv[j].y * f);
        sm.a.xt[d + 2][u] = f2bf(xv[j].z * f);
        sm.a.xt[d + 3][u] = f2bf(xv[j].w * f);
    }
    __syncthreads();

    const int fr = lane >> 4, fc = lane & 15;
    bf16x8 afr0 = *(const bf16x8*)&sm.a.xt[16 * w + fc][fr * 8];
    bf16x8 afr1 = *(const bf16x8*)&sm.a.xt[16 * w + fc][32 + fr * 8];
    f32x4 accs[8];
    #pragma unroll
    for (int st = 0; st < 8; ++st) {
        f32x4 acc = {0.f, 0.f, 0.f, 0.f};
        bf16x8 b0 = *(const bf16x8*)&sm.a.bt[st * 16 + fc][fr * 8];
        bf16x8 b1 = *(const bf16x8*)&sm.a.bt[st * 16 + fc][32 + fr * 8];
        acc = __builtin_amdgcn_mfma_f32_16x16x32_bf16(afr0, b0, acc, 0, 0, 0);
        acc = __builtin_amdgcn_mfma_f32_16x16x32_bf16(afr1, b1, acc, 0, 0, 0);
        accs[st] = acc;
    }
    __syncthreads();

    #pragma unroll
    for (int st = 0; st < 8; ++st) {
        #pragma unroll
        for (int r = 0; r < 4; ++r)
            sm.g[16 * w + fr * 4 + r][st * 16 + fc] = f2bf(accs[st][r]);
    }
    __syncthreads();

    const int gr = tid >> 2;
    unsigned short* gbase = G_ws + (((size_t)bh * NC + c) * DHh + gr) * DSs;
    #pragma unroll
    for (int j = 0; j < 4; ++j) {
        const int s = (j * 4 + q) * 8;
        *(uint4*)(gbase + s) = *(const uint4*)&sm.g[gr][s];
    }
}

// ============ K2: chunk-level scan over [d][s] planes ============
// 1536 one-wave blocks (6 waves/CU, was 3): 2 d-rows per wave, uint2 (8B/lane)
// loads, depth-16 rolling prefetch. Same aggregate bytes in flight, 2x the
// independent 32-step dependent-FMA chains to hide latency.
__global__ __launch_bounds__(64)
void k2_scan(const float* __restrict__ S_ws, const unsigned short* __restrict__ G_ws,
             unsigned short* __restrict__ H_ws) {
    const int bh = blockIdx.x >> 5;            // 48
    const int dp = blockIdx.x & 31;            // d-pair index
    const int tid = threadIdx.x;               // 64
    const int d  = dp * 2 + (tid >> 5);
    const int s0 = (tid & 31) * 4;

    float h[4];
    #pragma unroll
    for (int k = 0; k < 4; ++k) h[k] = 0.f;

    size_t base = (((size_t)bh * NC) * DHh + d) * DSs + s0;
    const size_t cstride = (size_t)DHh * DSs;
    const float* Se = S_ws + (size_t)bh * LSEQ + (TCH - 1);

    uint2 g[16]; float sv[16];
    #pragma unroll
    for (int j = 0; j < 16; ++j) {
        g[j]  = *(const uint2*)(G_ws + base + (size_t)j * cstride);
        sv[j] = Se[(size_t)j * TCH];
    }
    #pragma unroll
    for (int c = 0; c < NC; c += 16) {
        #pragma unroll
        for (int j = 0; j < 16; ++j) {
            const int cc = c + j;
            uint2 p;
            p.x = pk2(h[0], h[1]); p.y = pk2(h[2], h[3]);
            *(uint2*)(H_ws + base + (size_t)cc * cstride) = p;
            const float e = expf(sv[j]);
            const unsigned gu[2] = {g[j].x, g[j].y};
            #pragma unroll
            for (int k = 0; k < 2; ++k) {
                h[2 * k]     = fmaf(e, h[2 * k],     bf2f((unsigned short)(gu[k] & 0xffff)));
                h[2 * k + 1] = fmaf(e, h[2 * k + 1], bf2f((unsigned short)(gu[k] >> 16)));
            }
            if (cc + 16 < NC) {
                g[j]  = *(const uint2*)(G_ws + base + (size_t)(cc + 16) * cstride);
                sv[j] = Se[(size_t)(cc + 16) * TCH];
            }
        }
    }
}

// ============ K3: W = mask*exp o (C.B^T); y = W.X + E o (C.H^T), all MFMA ============
// (twice-verified R3 version: reg-built C fragments, padded separate sH,
//  swizzled linear sB; LDS ~52.3 KB -> 3 blocks/CU)
__global__ __launch_bounds__(256, 3)
void k3_y(const float* __restrict__ x, const float* __restrict__ Bm,
          const float* __restrict__ Cm, const float* __restrict__ S_ws,
          const unsigned short* __restrict__ H_ws, float* __restrict__ y) {
    __shared__ __align__(16) unsigned short sB[TCH * DSs];  // B [u][s] bf16, swizzled
    __shared__ __align__(16) unsigned short sH[DHh][SP];    // H [d][s] bf16, padded
    __shared__ __align__(16) unsigned short sW[TCH][UP];    // W [t][u] bf16
    __shared__ __align__(16) unsigned short sXT[DHh][UP];   // X^T [d][u] bf16
    __shared__ float sS[TCH];
    __shared__ float sEt[TCH];

    const int c  = blockIdx.x & (NC - 1);
    const int bh = blockIdx.x >> 5;
    const int nh = bh % NHh; const int b = bh / NHh;
    const int tid = threadIdx.x;
    const int lane = tid & 63;
    const int w = tid >> 6;
    const int fr = lane >> 4, fc = lane & 15;
    const int t0w = 16 * w;

    const size_t row0 = (size_t)(b * LSEQ + c * TCH) * NHh + nh;
    const int rr = tid >> 2;
    const int q  = tid & 3;
    const float* Brow = Bm + (row0 + (size_t)rr * NHh) * DSs;
    const float* xrow = x  + (row0 + (size_t)rr * NHh) * DHh;
    const unsigned short* Hrow = H_ws + (((size_t)bh * NC + c) * DHh + rr) * DSs;
    float4 bv[8], xv[4];
    uint4  hv[4];
    #pragma unroll
    for (int j = 0; j < 8; ++j) bv[j] = *(const float4*)(Brow + (j * 4 + q) * 4);
    #pragma unroll
    for (int j = 0; j < 4; ++j) xv[j] = *(const float4*)(xrow + (j * 4 + q) * 4);
    #pragma unroll
    for (int j = 0; j < 4; ++j) hv[j] = *(const uint4*)(Hrow + (j * 4 + q) * 8);

    const float* Cfr = Cm + (row0 + (size_t)(t0w + fc) * NHh) * DSs + fr * 8;
    float4 cf[8];
    #pragma unroll
    for (int kb = 0; kb < 4; ++kb) {
        cf[2 * kb]     = *(const float4*)(Cfr + kb * 32);
        cf[2 * kb + 1] = *(const float4*)(Cfr + kb * 32 + 4);
    }

    if (tid < 64) {
        float svv = S_ws[(size_t)bh * LSEQ + c * TCH + tid];
        sS[tid]  = svv;
        sEt[tid] = expf(svv);
    }

    bf16x8 ca[4];
    #pragma unroll
    for (int kb = 0; kb < 4; ++kb) {
        bf16x8 t;
        t[0] = (short)f2bf(cf[2 * kb].x);     t[1] = (short)f2bf(cf[2 * kb].y);
        t[2] = (short)f2bf(cf[2 * kb].z);     t[3] = (short)f2bf(cf[2 * kb].w);
        t[4] = (short)f2bf(cf[2 * kb + 1].x); t[5] = (short)f2bf(cf[2 * kb + 1].y);
        t[6] = (short)f2bf(cf[2 * kb + 1].z); t[7] = (short)f2bf(cf[2 * kb + 1].w);
        ca[kb] = t;
    }

    const int rsw = (rr & 15) << 3;   // sB swizzle: elem bits[6:3] ^= row&15
    #pragma unroll
    for (int j = 0; j < 8; ++j) {
        const int s = (j * 4 + q) * 4;
        *(uint2*)&sB[rr * DSs + (s ^ rsw)] =
            make_uint2(pk2(bv[j].x, bv[j].y), pk2(bv[j].z, bv[j].w));
    }
    #pragma unroll
    for (int j = 0; j < 4; ++j)
        *(uint4*)&sH[rr][(j * 4 + q) * 8] = hv[j];
    #pragma unroll
    for (int j = 0; j < 4; ++j) {
        const int d = (j * 4 + q) * 4;
        sXT[d + 0][rr] = f2bf(xv[j].x);
        sXT[d + 1][rr] = f2bf(xv[j].y);
        sXT[d + 2][rr] = f2bf(xv[j].z);
        sXT[d + 3][rr] = f2bf(xv[j].w);
    }
    __syncthreads();

    float st4[4];
    #pragma unroll
    for (int r = 0; r < 4; ++r) st4[r] = sS[t0w + fr * 4 + r];

    const int csw = fc << 3;          // read-side swizzle for sB row (u0+fc)
    #pragma unroll
    for (int ut = 0; ut < 4; ++ut) {
        const int u0 = ut * 16;
        unsigned short wv[4] = {0, 0, 0, 0};
        if (ut <= w) {   // tiles fully in the future are all-zero
            f32x4 acc = {0.f, 0.f, 0.f, 0.f};
            #pragma unroll
            for (int kb = 0; kb < 4; ++kb) {
                bf16x8 bb = *(const bf16x8*)
                    &sB[(u0 + fc) * DSs + ((kb * 32 + fr * 8) ^ csw)];
                acc = __builtin_amdgcn_mfma_f32_16x16x32_bf16(ca[kb], bb, acc, 0, 0, 0);
            }
            const float su = sS[u0 + fc];
            const int   uu = u0 + fc;
            #pragma unroll
            for (int r = 0; r < 4; ++r) {
                const int t = t0w + fr * 4 + r;
                const float dd = fminf(st4[r] - su, 0.f);
                const float val = (uu <= t) ? acc[r] * expf(dd) : 0.f;
                wv[r] = f2bf(val);
            }
        }
        #pragma unroll
        for (int r = 0; r < 4; ++r) sW[t0w + fr * 4 + r][u0 + fc] = wv[r];
    }
    // no __syncthreads: each wave reads only the sW rows it wrote

    bf16x8 wa0 = *(const bf16x8*)&sW[t0w + fc][fr * 8];
    bf16x8 wa1;
    if (w >= 2) wa1 = *(const bf16x8*)&sW[t0w + fc][32 + fr * 8];
    float et4[4];
    #pragma unroll
    for (int r = 0; r < 4; ++r) et4[r] = sEt[t0w + fr * 4 + r];

    #pragma unroll
    for (int dt = 0; dt < 4; ++dt) {
        const int d0 = dt * 16;
        f32x4 acc = {0.f, 0.f, 0.f, 0.f};
        #pragma unroll
        for (int kb = 0; kb < 4; ++kb) {
            bf16x8 hb = *(const bf16x8*)&sH[d0 + fc][kb * 32 + fr * 8];
            acc = __builtin_amdgcn_mfma_f32_16x16x32_bf16(ca[kb], hb, acc, 0, 0, 0);
        }
        #pragma unroll
        for (int r = 0; r < 4; ++r) acc[r] *= et4[r];
        bf16x8 xb0 = *(const bf16x8*)&sXT[d0 + fc][fr * 8];
        acc = __builtin_amdgcn_mfma_f32_16x16x32_bf16(wa0, xb0, acc, 0, 0, 0);
        if (w >= 2) {
            bf16x8 xb1 = *(const bf16x8*)&sXT[d0 + fc][32 + fr * 8];
            acc = __builtin_amdgcn_mfma_f32_16x16x32_bf16(wa1, xb1, acc, 0, 0, 0);
        }
        float* yout = y + (row0 + (size_t)(t0w + fr * 4) * NHh) * DHh + d0 + fc;
        #pragma unroll
        for (int r = 0; r < 4; ++r) yout[(size_t)r * NHh * DHh] = acc[r];
    }
}

// ============ fallback (R2 kernel) ============
__device__ __forceinline__ void gload_lds16(const float* g, void* l) {
    __builtin_amdgcn_global_load_lds(
        (const __attribute__((address_space(1))) void*)g,
        (__attribute__((address_space(3))) void*)l, 16, 0, 0);
}
__device__ __forceinline__ void gload_lds4(const float* g, float* l) {
    __builtin_amdgcn_global_load_lds(
        (const __attribute__((address_space(1))) void*)g,
        (__attribute__((address_space(3))) void*)l, 4, 0, 0);
}
#define F_DBLK 4
#define F_DPW 16
#define F_TCH 32
#define F_NCH (LSEQ / F_TCH)
__global__ __launch_bounds__(256, 1)
void ssm_scan_fb(const float* __restrict__ x, const float* __restrict__ A,
                 const float* __restrict__ Bm, const float* __restrict__ Cm,
                 const float* __restrict__ dp, float* __restrict__ y) {
    __shared__ float s_abar[LSEQ];
    __shared__ float s_B[2][F_TCH][DSs];
    __shared__ float s_C[2][F_TCH][DSs];
    __shared__ float s_x[2][F_TCH][F_DPW];
    const int blk = blockIdx.x;
    const int dblk = blk % F_DBLK, bh = blk / F_DBLK;
    const int nh = bh % NHh, b = bh / NHh;
    const float dpv = dp[nh];
    for (int i = threadIdx.x; i < LSEQ; i += 256) {
        float a = A[(b * LSEQ + i) * NHh + nh];
        float z = a + dpv;
        float sp = (z > 20.0f) ? z : log1pf(expf(z));
        s_abar[i] = expf(-sp * fabsf(a));
    }
    const int tid = threadIdx.x, wid = tid >> 6, lane = tid & 63;
    const int dloc = tid >> 4, sg = tid & 15, sb = sg * 8;
    const size_t bh_off = (size_t)(b * LSEQ) * NHh + nh;
    const float* Bbase = Bm + bh_off * DSs;
    const float* Cbase = Cm + bh_off * DSs;
    const float* xbase = x + bh_off * DHh + dblk * F_DPW;
    float* yp = y + bh_off * DHh + dblk * F_DPW + dloc;
    const int RSTRIDE = NHh * DSs, XSTRIDE = NHh * DHh;
    auto stage = [&](int buf, int t0) {
        #pragma unroll
        for (int j = 0; j < 4; ++j) {
            const int r0 = (wid * 4 + j) * 2, r = r0 + (lane >> 5), col = (lane & 31) * 4;
            gload_lds16(Bbase + (size_t)(t0 + r) * RSTRIDE + col, &s_B[buf][r0][0]);
            gload_lds16(Cbase + (size_t)(t0 + r) * RSTRIDE + col, &s_C[buf][r0][0]);
        }
        #pragma unroll
        for (int j = 0; j < 2; ++j) {
            const int idx = (wid * 2 + j) * 64 + lane, t = idx >> 4, dc = idx & 15;
            gload_lds4(xbase + (size_t)(t0 + t) * XSTRIDE + dc, &s_x[buf][(wid * 2 + j) * 4][0]);
        }
    };
    stage(0, 0);
    __syncthreads();
    float h0=0,h1=0,h2=0,h3=0,h4=0,h5=0,h6=0,h7=0;
    for (int c = 0; c < F_NCH; ++c) {
        const int buf = c & 1;
        if (c + 1 < F_NCH) stage(buf ^ 1, (c + 1) * F_TCH);
        const int t0 = c * F_TCH;
        #pragma unroll 4
        for (int tt = 0; tt < F_TCH; ++tt) {
            const int t = t0 + tt;
            const float a = s_abar[t], xd = s_x[buf][tt][dloc];
            const float4* Br = (const float4*)&s_B[buf][tt][sb];
            const float4* Cr = (const float4*)&s_C[buf][tt][sb];
            const float4 B0 = Br[0], B1 = Br[1], C0 = Cr[0], C1 = Cr[1];
            h0 = fmaf(a, h0, xd * B0.x); h1 = fmaf(a, h1, xd * B0.y);
            h2 = fmaf(a, h2, xd * B0.z); h3 = fmaf(a, h3, xd * B0.w);
            h4 = fmaf(a, h4, xd * B1.x); h5 = fmaf(a, h5, xd * B1.y);
            h6 = fmaf(a, h6, xd * B1.z); h7 = fmaf(a, h7, xd * B1.w);
            float p0 = h0 * C0.x; p0 = fmaf(h1, C0.y, p0); p0 = fmaf(h2, C0.z, p0); p0 = fmaf(h3, C0.w, p0);
            float p1 = h4 * C1.x; p1 = fmaf(h5, C1.y, p1); p1 = fmaf(h6, C1.z, p1); p1 = fmaf(h7, C1.w, p1);
            float p = p0 + p1;
            p += __shfl_xor(p, 1, 64); p += __shfl_xor(p, 2, 64);
            p += __shfl_xor(p, 4, 64); p += __shfl_xor(p, 8, 64);
            if (sg == 0) yp[(size_t)t * XSTRIDE] = p;
        }
        __syncthreads();
    }
}

extern "C" void kernel_launch(void* const* d_in, const int* in_sizes, int n_in,
                              void* d_out, int out_size, void* d_ws, size_t ws_size,
                              hipStream_t stream) {
    const float* x  = (const float*)d_in[0];
    const float* A  = (const float*)d_in[1];
    const float* Bm = (const float*)d_in[2];
    const float* Cm = (const float*)d_in[3];
    const float* dp = (const float*)d_in[4];
    float* y = (float*)d_out;

    if (ws_size >= WS_REQ) {
        float* S_ws = (float*)d_ws;
        unsigned short* G_ws = (unsigned short*)((char*)d_ws + WS_S_BYTES);
        unsigned short* H_ws = G_ws + G_ELEMS;
        hipLaunchKernelGGL(k1_chunk, dim3(BH * NC), dim3(256), 0, stream,
                           x, A, Bm, dp, S_ws, G_ws);
        hipLaunchKernelGGL(k2_scan, dim3(BH * 32), dim3(64), 0, stream,
                           S_ws, G_ws, H_ws);
        hipLaunchKernelGGL(k3_y, dim3(BH * NC), dim3(256), 0, stream,
                           x, Bm, Cm, S_ws, H_ws, y);
    } else {
        hipLaunchKernelGGL(ssm_scan_fb, dim3(BH * F_DBLK), dim3(256), 0, stream,
                           x, A, Bm, Cm, dp, y);
    }
}